// Round 4
// baseline (84.079 us; speedup 1.0000x reference)
//
#include <hip/hip_runtime.h>
#include <hip/hip_bf16.h>

// out[b,i,j,o] = Y''[b*128+i][o] + Y''[b*128+j][o]
// where Y''[m][o] = sum_h L[m][h] * W[o][h] + 0.5*bias[o]   (M=1024, O=512, H=512)

typedef float f4 __attribute__((ext_vector_type(4)));

// ---- Kernel 1: transpose W[o][k] -> Wt[k][o], 512x512 fp32 ----
__global__ __launch_bounds__(256) void transpose_w(const float* __restrict__ W,
                                                   float* __restrict__ Wt) {
    __shared__ float T[64][65];
    const int bx = blockIdx.x;   // k-tile
    const int by = blockIdx.y;   // o-tile
    const int tid = threadIdx.x;
    const int rr = tid >> 4;     // 0..15
    const int c4 = tid & 15;     // 0..15

    #pragma unroll
    for (int i = 0; i < 4; ++i) {
        const int r = rr + 16 * i;
        const f4 v = *(const f4*)&W[(by * 64 + r) * 512 + bx * 64 + c4 * 4];
        T[r][c4 * 4 + 0] = v.x; T[r][c4 * 4 + 1] = v.y;
        T[r][c4 * 4 + 2] = v.z; T[r][c4 * 4 + 3] = v.w;
    }
    __syncthreads();
    #pragma unroll
    for (int i = 0; i < 4; ++i) {
        const int r = rr + 16 * i;          // k within tile
        f4 v;
        v.x = T[c4 * 4 + 0][r]; v.y = T[c4 * 4 + 1][r];
        v.z = T[c4 * 4 + 2][r]; v.w = T[c4 * 4 + 3][r];
        *(f4*)&Wt[(bx * 64 + r) * 512 + by * 64 + c4 * 4] = v;
    }
}

// ---- Kernel 2: Y''[m][o] = A[m]·Wt[:,o] + 0.5*b[o] ----
// 256 blocks, one per 4 m-rows. 256 threads: halves split K, lanes own o (f4).
// No LDS in the hot loop: Wt rows stream from L2 coalesced, A is a
// wave-uniform broadcast load. K-halves combined via one LDS pass.
__global__ __launch_bounds__(256) void gemm_stream(const float* __restrict__ A,
                                                   const f4* __restrict__ Wt4,
                                                   const f4* __restrict__ b4,
                                                   f4* __restrict__ Y4) {
    __shared__ f4 part[128][4];
    const int tid = threadIdx.x;
    const int h  = __builtin_amdgcn_readfirstlane(tid >> 7);  // wave-uniform k-half
    const int o4 = tid & 127;                                 // 0..127 -> o = o4*4
    const int m0 = blockIdx.x * 4;

    f4 acc0 = {0,0,0,0}, acc1 = {0,0,0,0}, acc2 = {0,0,0,0}, acc3 = {0,0,0,0};

    const int kbase = h * 256;
    const float* __restrict__ Ar = A + m0 * 512 + kbase;
    const f4* __restrict__ wp = Wt4 + (size_t)kbase * 128 + o4;

    #pragma unroll 4
    for (int k4 = 0; k4 < 64; ++k4) {
        const int k = k4 * 4;
        const f4 a0 = *(const f4*)&Ar[0 * 512 + k];
        const f4 a1 = *(const f4*)&Ar[1 * 512 + k];
        const f4 a2 = *(const f4*)&Ar[2 * 512 + k];
        const f4 a3 = *(const f4*)&Ar[3 * 512 + k];
        const f4 w0 = wp[(k + 0) * 128];
        const f4 w1 = wp[(k + 1) * 128];
        const f4 w2 = wp[(k + 2) * 128];
        const f4 w3 = wp[(k + 3) * 128];
        acc0 += a0.x * w0 + a0.y * w1 + a0.z * w2 + a0.w * w3;
        acc1 += a1.x * w0 + a1.y * w1 + a1.z * w2 + a1.w * w3;
        acc2 += a2.x * w0 + a2.y * w1 + a2.z * w2 + a2.w * w3;
        acc3 += a3.x * w0 + a3.y * w1 + a3.z * w2 + a3.w * w3;
    }

    if (h == 1) {
        part[tid - 128][0] = acc0; part[tid - 128][1] = acc1;
        part[tid - 128][2] = acc2; part[tid - 128][3] = acc3;
    }
    __syncthreads();
    if (h == 0) {
        const f4 bb = 0.5f * b4[o4];
        acc0 += part[tid][0] + bb;
        acc1 += part[tid][1] + bb;
        acc2 += part[tid][2] + bb;
        acc3 += part[tid][3] + bb;
        Y4[(m0 + 0) * 128 + o4] = acc0;
        Y4[(m0 + 1) * 128 + o4] = acc1;
        Y4[(m0 + 2) * 128 + o4] = acc2;
        Y4[(m0 + 3) * 128 + o4] = acc3;
    }
}

// ---- Kernel 3: out[b,i,j,:] = Y''[b,i,:] + Y''[b,j,:] ----
__global__ __launch_bounds__(256) void pair_add(const f4* __restrict__ Y4,
                                                f4* __restrict__ out4) {
    const int blk = blockIdx.x;          // b*128 + i
    const int t   = threadIdx.x;
    const int o4  = t & 127;
    const int jh  = t >> 7;

    const f4 yib = Y4[blk * 128 + o4];
    const f4* __restrict__ Yb = Y4 + (blk >> 7) * (128 * 128);
    f4* __restrict__ orow = out4 + blk * (128 * 128);

    #pragma unroll 4
    for (int j = jh; j < 128; j += 2) {
        const f4 r = yib + Yb[j * 128 + o4];
        __builtin_nontemporal_store(r, &orow[j * 128 + o4]);
    }
}

extern "C" void kernel_launch(void* const* d_in, const int* in_sizes, int n_in,
                              void* d_out, int out_size, void* d_ws, size_t ws_size,
                              hipStream_t stream) {
    const float* L = (const float*)d_in[0];   // [8,128,512]
    const float* W = (const float*)d_in[1];   // [512,512]
    const float* b = (const float*)d_in[2];   // [512]
    float* out = (float*)d_out;               // [8,128,128,512]
    float* Y   = (float*)d_ws;                              // 2 MiB
    float* Wt  = (float*)((char*)d_ws + (2u << 20));        // 1 MiB

    transpose_w<<<dim3(8, 8), 256, 0, stream>>>(W, Wt);
    gemm_stream<<<256, 256, 0, stream>>>(L, (const f4*)Wt, (const f4*)b, (f4*)Y);
    pair_add<<<1024, 256, 0, stream>>>((const f4*)Y, (f4*)out);
    (void)in_sizes; (void)n_in; (void)out_size; (void)ws_size;
}

// Round 5
// 77.747 us; speedup vs baseline: 1.0814x; 1.0814x over previous
//
#include <hip/hip_runtime.h>
#include <hip/hip_bf16.h>

// out[b,i,j,o] = Y[b*128+i][o] + Y[b*128+j][o] + bias[o]
// where Y[m][o] = sum_h L[m][h] * W[o][h]   (M=1024, O=512, H=512)

typedef float f4 __attribute__((ext_vector_type(4)));

#define BM 32
#define BO 64
#define BK 32
#define LDS_PAD 36   // row stride in floats: 144B, multiple of 16B -> aligned f4

__global__ __launch_bounds__(256) void gemm_lwt(const float* __restrict__ A,
                                                const float* __restrict__ W,
                                                float* __restrict__ Y) {
    __shared__ __align__(16) float As[BM][LDS_PAD];
    __shared__ __align__(16) float Ws[BO][LDS_PAD];

    const int tid = threadIdx.x;
    const int m0 = blockIdx.x * BM;   // gridDim.x = 1024/32 = 32
    const int o0 = blockIdx.y * BO;   // gridDim.y = 512/64  = 8
    const int tm = tid >> 4;          // 0..15 -> rows tm*2+ii
    const int to = tid & 15;          // 0..15 -> cols to+16*jj

    float acc[2][4] = {};

    for (int kt = 0; kt < 512; kt += BK) {
        {
            const int row = tid >> 3;        // 0..31
            const int k4  = tid & 7;
            *(f4*)&As[row][k4 * 4] = *(const f4*)&A[(m0 + row) * 512 + kt + k4 * 4];
        }
        #pragma unroll
        for (int l = 0; l < 2; ++l) {
            const int fid = tid + l * 256;
            const int row = fid >> 3;        // 0..63
            const int k4  = fid & 7;
            *(f4*)&Ws[row][k4 * 4] = *(const f4*)&W[(o0 + row) * 512 + kt + k4 * 4];
        }
        __syncthreads();

        #pragma unroll
        for (int k0 = 0; k0 < BK; k0 += 4) {
            f4 a4[2], w4[4];
            #pragma unroll
            for (int ii = 0; ii < 2; ++ii) a4[ii] = *(const f4*)&As[tm * 2 + ii][k0];
            #pragma unroll
            for (int jj = 0; jj < 4; ++jj) w4[jj] = *(const f4*)&Ws[to + 16 * jj][k0];
            #pragma unroll
            for (int ii = 0; ii < 2; ++ii)
                #pragma unroll
                for (int jj = 0; jj < 4; ++jj)
                    acc[ii][jj] += a4[ii].x * w4[jj].x + a4[ii].y * w4[jj].y +
                                   a4[ii].z * w4[jj].z + a4[ii].w * w4[jj].w;
        }
        __syncthreads();
    }

    #pragma unroll
    for (int ii = 0; ii < 2; ++ii)
        #pragma unroll
        for (int jj = 0; jj < 4; ++jj)
            Y[(m0 + tm * 2 + ii) * 512 + o0 + to + 16 * jj] = acc[ii][jj];
}

// 2048 blocks: block = (b*128+i)*2 + jhalf. Each block writes 64 rows
// (128 KB contiguous). 8 blocks/CU -> 32 waves/CU for full latency hiding.
__global__ __launch_bounds__(256) void pair_add(const f4* __restrict__ Y4,
                                                const f4* __restrict__ b4,
                                                f4* __restrict__ out4) {
    const int blk = blockIdx.x;
    const int bi  = blk >> 1;            // b*128 + i
    const int j0  = (blk & 1) << 6;      // 0 or 64
    const int t   = threadIdx.x;
    const int o4  = t & 127;             // 0..127 (128 f4 per row)
    const int jh  = t >> 7;              // 0 or 1

    const f4 yib = Y4[bi * 128 + o4] + b4[o4];
    const f4* __restrict__ Yb = Y4 + (bi >> 7) * (128 * 128);
    f4* __restrict__ orow = out4 + bi * (128 * 128);

    #pragma unroll 4
    for (int j = j0 + jh; j < j0 + 64; j += 2) {
        const f4 r = yib + Yb[j * 128 + o4];
        __builtin_nontemporal_store(r, &orow[j * 128 + o4]);
    }
}

extern "C" void kernel_launch(void* const* d_in, const int* in_sizes, int n_in,
                              void* d_out, int out_size, void* d_ws, size_t ws_size,
                              hipStream_t stream) {
    const float* L = (const float*)d_in[0];   // [8,128,512]
    const float* W = (const float*)d_in[1];   // [512,512]
    const float* b = (const float*)d_in[2];   // [512]
    float* out = (float*)d_out;               // [8,128,128,512]
    float* Y   = (float*)d_ws;                // [1024,512] scratch, 2 MiB

    dim3 g1(32, 8);
    gemm_lwt<<<g1, 256, 0, stream>>>(L, W, Y);

    pair_add<<<2048, 256, 0, stream>>>((const f4*)Y, (const f4*)b, (f4*)out);
    (void)in_sizes; (void)n_in; (void)out_size; (void)ws_size;
}